// Round 4
// baseline (694.532 us; speedup 1.0000x reference)
//
#include <hip/hip_runtime.h>
#include <hip/hip_bf16.h>
#include <stdint.h>

#define T_DIM 4096
#define D_DIM 768
#define NHEAD 12
#define HDIM 64

typedef __attribute__((ext_vector_type(8))) short s16x8;
typedef __attribute__((ext_vector_type(4))) float f32x4;

__device__ __forceinline__ short f2bf(float f) {
  union { float f; uint32_t u; } v; v.f = f;
  uint32_t r = v.u + 0x7fffu + ((v.u >> 16) & 1u);
  return (short)(r >> 16);
}

// ---------------- fp32 -> bf16 convert (vectorized) ----------------
__global__ void cvt_x_kernel(const float* __restrict__ x, short* __restrict__ xb) {
  int i = (blockIdx.x * blockDim.x + threadIdx.x) * 8;
  float4 a = *(const float4*)(x + i);
  float4 b = *(const float4*)(x + i + 4);
  s16x8 o;
  o[0] = f2bf(a.x); o[1] = f2bf(a.y); o[2] = f2bf(a.z); o[3] = f2bf(a.w);
  o[4] = f2bf(b.x); o[5] = f2bf(b.y); o[6] = f2bf(b.z); o[7] = f2bf(b.w);
  *(s16x8*)(xb + i) = o;
}

// ---------------- W (fp32 [K][N]) -> Wt (bf16 [N][K]) ----------------
__global__ void transpose_w_kernel(const float* __restrict__ W, short* __restrict__ Wt) {
  __shared__ short tile[64][65];
  int kb = blockIdx.x * 64, nb = blockIdx.y * 64;
  for (int idx = threadIdx.x; idx < 4096; idx += 256) {
    int r = idx >> 6, c = idx & 63;
    tile[r][c] = f2bf(W[(kb + r) * D_DIM + nb + c]);
  }
  __syncthreads();
  for (int idx = threadIdx.x; idx < 4096; idx += 256) {
    int r = idx >> 6, c = idx & 63;
    Wt[(nb + r) * D_DIM + kb + c] = tile[c][r];
  }
}

// ---------------- V (bf16 [T][D]) -> Vt (bf16 [D][T]), key-permuted ----------------
// Within each 64-key block, keys are stored at permuted position
//   sigma(c) = (c & 15) * 4 + (c >> 4)
// so that the attention kernel's P-staging (pairs along kt) and V reads agree.
__global__ void transpose_v_kernel(const short* __restrict__ V, short* __restrict__ Vt) {
  __shared__ short tile[64][65];
  int tb = blockIdx.x * 64, cb = blockIdx.y * 64;
  for (int idx = threadIdx.x; idx < 4096; idx += 256) {
    int r = idx >> 6, c = idx & 63;
    tile[r][c] = V[(tb + r) * D_DIM + cb + c];
  }
  __syncthreads();
  for (int idx = threadIdx.x; idx < 4096; idx += 256) {
    int r = idx >> 6, c = idx & 63;
    int perm = (c & 15) * 4 + (c >> 4);
    Vt[(cb + r) * T_DIM + tb + perm] = tile[c][r];
  }
}

// ---------------- mask (int32 0/1 [T][T]) -> bitmap (u64 [T][T/64]) ----------------
__global__ void pack_mask_kernel(const int* __restrict__ mask,
                                 unsigned long long* __restrict__ bits) {
  int gid = blockIdx.x * 256 + threadIdx.x;
  unsigned long long b = __ballot(mask[gid] != 0);
  if ((threadIdx.x & 63) == 0) bits[gid >> 6] = b;
}

// ---- shared GEMM body: 64x64 tile, 4 waves, K-step 32, global_load_lds staging ----
#define GEMM_BODY(As, Bs, Aptr, Btptr, K_)                                             \
  int tid = threadIdx.x;                                                               \
  int lane = tid & 63, w = tid >> 6;                                                   \
  int wm = w >> 1, wn = w & 1;                                                         \
  int mb = blockIdx.x * 64, nb = blockIdx.y * 64;                                      \
  int srow = lane >> 2, scol = (lane & 3) * 8;                                         \
  int fr = lane & 15, fk = (lane >> 4) * 8;                                            \
  f32x4 acc[2][2] = {};                                                                \
  for (int k0 = 0; k0 < K_; k0 += 32) {                                                \
    const short* ga = Aptr + (long)(mb + w * 16 + srow) * K_ + k0 + scol;              \
    const short* gb = Btptr + (long)(nb + w * 16 + srow) * K_ + k0 + scol;             \
    __builtin_amdgcn_global_load_lds(                                                  \
        (const __attribute__((address_space(1))) void*)ga,                             \
        (__attribute__((address_space(3))) void*)&As[w * 16][0], 16, 0, 0);            \
    __builtin_amdgcn_global_load_lds(                                                  \
        (const __attribute__((address_space(1))) void*)gb,                             \
        (__attribute__((address_space(3))) void*)&Bs[w * 16][0], 16, 0, 0);            \
    __syncthreads();                                                                   \
    s16x8 af[2], bfr[2];                                                               \
    af[0] = *(const s16x8*)&As[wm * 32 + fr][fk];                                      \
    af[1] = *(const s16x8*)&As[wm * 32 + 16 + fr][fk];                                 \
    bfr[0] = *(const s16x8*)&Bs[wn * 32 + fr][fk];                                     \
    bfr[1] = *(const s16x8*)&Bs[wn * 32 + 16 + fr][fk];                                \
    _Pragma("unroll") for (int mr = 0; mr < 2; mr++)                                   \
        _Pragma("unroll") for (int nr = 0; nr < 2; nr++)                               \
            acc[mr][nr] = __builtin_amdgcn_mfma_f32_16x16x32_bf16(                     \
                af[mr], bfr[nr], acc[mr][nr], 0, 0, 0);                                \
    __syncthreads();                                                                   \
  }                                                                                    \
  int fg = lane >> 4;

// Fused QKV GEMM: blockIdx.z selects {Wq,Wk,Wv} (wave-uniform select).
__global__ __launch_bounds__(256)
void gemm_qkv_kernel(const short* __restrict__ A,
                     const short* __restrict__ Bt0, const short* __restrict__ Bt1,
                     const short* __restrict__ Bt2,
                     const float* __restrict__ bias0, const float* __restrict__ bias1,
                     const float* __restrict__ bias2,
                     short* __restrict__ C0, short* __restrict__ C1,
                     short* __restrict__ C2) {
  __shared__ short As[64][32];
  __shared__ short Bs[64][32];
  int z = blockIdx.z;
  const short* Bt = (z == 0) ? Bt0 : (z == 1) ? Bt1 : Bt2;
  const float* bias = (z == 0) ? bias0 : (z == 1) ? bias1 : bias2;
  short* C = (z == 0) ? C0 : (z == 1) ? C1 : C2;
  GEMM_BODY(As, Bs, A, Bt, D_DIM)
#pragma unroll
  for (int mr = 0; mr < 2; mr++)
#pragma unroll
    for (int nr = 0; nr < 2; nr++)
#pragma unroll
      for (int i = 0; i < 4; i++) {
        int row = mb + wm * 32 + mr * 16 + fg * 4 + i;
        int col = nb + wn * 32 + nr * 16 + fr;
        C[(long)row * D_DIM + col] = f2bf(acc[mr][nr][i] + bias[col]);
      }
}

// O-projection GEMM (fp32 out).
__global__ __launch_bounds__(256)
void gemm_o_kernel(const short* __restrict__ A, const short* __restrict__ Bt,
                   const float* __restrict__ bias, float* __restrict__ C) {
  __shared__ short As[64][32];
  __shared__ short Bs[64][32];
  GEMM_BODY(As, Bs, A, Bt, D_DIM)
#pragma unroll
  for (int mr = 0; mr < 2; mr++)
#pragma unroll
    for (int nr = 0; nr < 2; nr++)
#pragma unroll
      for (int i = 0; i < 4; i++) {
        int row = mb + wm * 32 + mr * 16 + fg * 4 + i;
        int col = nb + wn * 32 + nr * 16 + fr;
        C[(long)row * D_DIM + col] = acc[mr][nr][i] + bias[col];
      }
}

// ---------------- fused attention ----------------
// grid (T/128, NH), 512 threads (8 waves), wave = 16 q-rows.
// 64-key inner step. masked_fill -> 1e-20 (NOT -inf: masked entries contribute
// exp(1e-20)=1 to the denominator). p = exp(s) without max-subtraction
// (|s| <~ 20, fp32-safe; exactly softmax after the final normalize).
// P staged in LDS in sigma-permuted key order (sigma(k)=(k&15)*4+(k>>4)):
// each lane's 4 kt-values are contiguous -> 2x v_cvt_pk_bf16_f32 + ds_write_b64.
// V was pre-permuted with the same sigma in transpose_v, so PV sums match.
__global__ __launch_bounds__(512)
void attn_kernel(const short* __restrict__ Q, const short* __restrict__ Kb,
                 const short* __restrict__ Vt,
                 const unsigned long long* __restrict__ mbits,
                 short* __restrict__ O) {
  __shared__ short Plds[8][16][72];  // rows 144 B: 16B-aligned reads, 8B-aligned writes
  int tid = threadIdx.x;
  int lane = tid & 63, w = tid >> 6;
  int h = blockIdx.y;
  int q0 = blockIdx.x * 128 + w * 16;
  int fr = lane & 15, fg = lane >> 4;

  const short* qp = Q + (long)(q0 + fr) * D_DIM + h * HDIM + fg * 8;
  s16x8 qf0 = *(const s16x8*)qp;
  s16x8 qf1 = *(const s16x8*)(qp + 32);

  const short* vrow[4];
#pragma unroll
  for (int dt = 0; dt < 4; dt++)
    vrow[dt] = Vt + (long)(h * HDIM + dt * 16 + fr) * T_DIM + fg * 8;

  const unsigned long long* mrow = mbits + (long)(q0 + fg * 4) * (T_DIM / 64);

  f32x4 oacc[4] = {};
  float lsum[4] = {0.f, 0.f, 0.f, 0.f};

  for (int kb = 0; kb < T_DIM / 64; kb++) {
    int key0 = kb * 64;

    // QK^T for 4 key-subtiles of 16 (original key order)
    f32x4 s[4];
#pragma unroll
    for (int kt = 0; kt < 4; kt++) {
      const short* kp = Kb + (long)(key0 + kt * 16 + fr) * D_DIM + h * HDIM + fg * 8;
      s16x8 kf0 = *(const s16x8*)kp;
      s16x8 kf1 = *(const s16x8*)(kp + 32);
      f32x4 z = {};
      z = __builtin_amdgcn_mfma_f32_16x16x32_bf16(qf0, kf0, z, 0, 0, 0);
      z = __builtin_amdgcn_mfma_f32_16x16x32_bf16(qf1, kf1, z, 0, 0, 0);
      s[kt] = z;
    }

    // mask -> 1e-20, exp, partial sums, pack pairs, stage P to LDS (b64)
#pragma unroll
    for (int i = 0; i < 4; i++) {
      unsigned long long wsh = mrow[(long)i * (T_DIM / 64) + kb] >> fr;
      uint32_t wlo = (uint32_t)wsh, whi = (uint32_t)(wsh >> 32);
      float p[4];
      p[0] = __expf((wlo & 1u)         ? 1e-20f : s[0][i]); lsum[i] += p[0];
      p[1] = __expf(((wlo >> 16) & 1u) ? 1e-20f : s[1][i]); lsum[i] += p[1];
      p[2] = __expf((whi & 1u)         ? 1e-20f : s[2][i]); lsum[i] += p[2];
      p[3] = __expf(((whi >> 16) & 1u) ? 1e-20f : s[3][i]); lsum[i] += p[3];
      uint32_t plo, phi;  // v_cvt_pk_bf16_f32: D[15:0]=bf16(src0), D[31:16]=bf16(src1)
      asm("v_cvt_pk_bf16_f32 %0, %1, %2" : "=v"(plo) : "v"(p[0]), "v"(p[1]));
      asm("v_cvt_pk_bf16_f32 %0, %1, %2" : "=v"(phi) : "v"(p[2]), "v"(p[3]));
      // shorts [fr*4 .. fr*4+3] of row fg*4+i  (sigma-permuted key positions)
      *(uint2*)&Plds[w][fg * 4 + i][fr * 4] = make_uint2(plo, phi);
    }
    asm volatile("s_waitcnt lgkmcnt(0)" ::: "memory");  // wave-synchronous LDS handoff
    s16x8 pf0 = *(const s16x8*)&Plds[w][fr][fg * 8];
    s16x8 pf1 = *(const s16x8*)&Plds[w][fr][32 + fg * 8];
#pragma unroll
    for (int dt = 0; dt < 4; dt++) {
      s16x8 vf0 = *(const s16x8*)(vrow[dt] + key0);
      s16x8 vf1 = *(const s16x8*)(vrow[dt] + key0 + 32);
      oacc[dt] = __builtin_amdgcn_mfma_f32_16x16x32_bf16(pf0, vf0, oacc[dt], 0, 0, 0);
      oacc[dt] = __builtin_amdgcn_mfma_f32_16x16x32_bf16(pf1, vf1, oacc[dt], 0, 0, 0);
    }
  }
  // full row sums: butterfly over the 16-lane column group
#pragma unroll
  for (int i = 0; i < 4; i++) {
    float v = lsum[i];
    v += __shfl_xor(v, 1);
    v += __shfl_xor(v, 2);
    v += __shfl_xor(v, 4);
    v += __shfl_xor(v, 8);
    lsum[i] = 1.0f / v;
  }
#pragma unroll
  for (int dt = 0; dt < 4; dt++)
#pragma unroll
    for (int i = 0; i < 4; i++)
      O[(long)(q0 + fg * 4 + i) * D_DIM + h * HDIM + dt * 16 + fr] =
          f2bf(oacc[dt][i] * lsum[i]);
}

// ---------------- launch ----------------
extern "C" void kernel_launch(void* const* d_in, const int* in_sizes, int n_in,
                              void* d_out, int out_size, void* d_ws, size_t ws_size,
                              hipStream_t stream) {
  const float* x  = (const float*)d_in[0];
  const int* mask = (const int*)d_in[1];
  const float* Wq = (const float*)d_in[2];
  const float* bq = (const float*)d_in[3];
  const float* Wk = (const float*)d_in[4];
  const float* bk = (const float*)d_in[5];
  const float* Wv = (const float*)d_in[6];
  const float* bv = (const float*)d_in[7];
  const float* Wo = (const float*)d_in[8];
  const float* bo = (const float*)d_in[9];

  char* ws = (char*)d_ws;
  size_t off = 0;
  auto alloc = [&](size_t bytes) {
    void* p = ws + off;
    off += (bytes + 255) & ~(size_t)255;
    return p;
  };
  const size_t TD2 = (size_t)T_DIM * D_DIM * 2;
  const size_t DD2 = (size_t)D_DIM * D_DIM * 2;
  short* xb  = (short*)alloc(TD2);
  short* WqT = (short*)alloc(DD2);
  short* WkT = (short*)alloc(DD2);
  short* WvT = (short*)alloc(DD2);
  short* WoT = (short*)alloc(DD2);
  short* qb  = (short*)alloc(TD2);
  short* kbf = (short*)alloc(TD2);
  short* vb  = (short*)alloc(TD2);
  short* Vt  = (short*)alloc(TD2);
  short* Ob  = (short*)alloc(TD2);
  unsigned long long* mbits =
      (unsigned long long*)alloc((size_t)T_DIM * (T_DIM / 64) * 8);

  cvt_x_kernel<<<T_DIM * D_DIM / (256 * 8), 256, 0, stream>>>(x, xb);
  transpose_w_kernel<<<dim3(12, 12), 256, 0, stream>>>(Wq, WqT);
  transpose_w_kernel<<<dim3(12, 12), 256, 0, stream>>>(Wk, WkT);
  transpose_w_kernel<<<dim3(12, 12), 256, 0, stream>>>(Wv, WvT);
  transpose_w_kernel<<<dim3(12, 12), 256, 0, stream>>>(Wo, WoT);
  pack_mask_kernel<<<T_DIM * T_DIM / 256, 256, 0, stream>>>(mask, mbits);

  gemm_qkv_kernel<<<dim3(64, 12, 3), 256, 0, stream>>>(
      xb, WqT, WkT, WvT, bq, bk, bv, qb, kbf, vb);

  transpose_v_kernel<<<dim3(64, 12), 256, 0, stream>>>(vb, Vt);

  attn_kernel<<<dim3(32, 12), 512, 0, stream>>>(qb, kbf, Vt, mbits, Ob);

  gemm_o_kernel<<<dim3(64, 12), 256, 0, stream>>>(Ob, WoT, bo, (float*)d_out);
}